// Round 9
// baseline (335.922 us; speedup 1.0000x reference)
//
#include <hip/hip_runtime.h>

#define QSIZE 4194304          // B*D*H*W
#define THR   1.5e-4f          // certification threshold (error bound 9e-5 x 1.7 slack)

// ws layout (bytes)
#define WS_E2   0              // float[1024]
#define WS_EH   4096           // ushort[65536] bf16 hi of emb
#define WS_EL   135168         // ushort[65536] bf16 lo of emb
#define WS_IND  266240         // ushort[65536] argmin index per row
#define WS_CNT  397312         // uint rescue count
#define WS_LIST 397328         // ushort[65536] rescue row list

typedef __attribute__((ext_vector_type(8))) short short8;
typedef __attribute__((ext_vector_type(4))) float f32x4;

__device__ inline ushort bf16_rne(float v) {
    union { float f; unsigned u; } a; a.f = v;
    return (ushort)((a.u + 0x7FFFu + ((a.u >> 16) & 1u)) >> 16);
}
__device__ inline float bf16_f(ushort h) {
    union { unsigned u; float f; } a; a.u = ((unsigned)h) << 16;
    return a.f;
}

// ---- k0: e2 (numpy pairwise-8 replica) + eh/el bf16 split + zero cnt/losses ----
__global__ void k0_prep(const float* __restrict__ emb, float* __restrict__ e2,
                        ushort* __restrict__ eh, ushort* __restrict__ el,
                        unsigned* __restrict__ cnt, float* __restrict__ out) {
    #pragma clang fp contract(off)
    int k = blockIdx.x * 256 + threadIdx.x;       // grid 4
    const float* e = emb + k * 64;
    float r[8];
    #pragma unroll
    for (int q = 0; q < 8; ++q) r[q] = e[q] * e[q];
    #pragma unroll
    for (int i = 8; i < 64; i += 8) {
        #pragma unroll
        for (int q = 0; q < 8; ++q) r[q] = r[q] + e[i + q] * e[i + q];
    }
    e2[k] = ((r[0] + r[1]) + (r[2] + r[3])) + ((r[4] + r[5]) + (r[6] + r[7]));
    #pragma unroll 4
    for (int d = 0; d < 64; ++d) {
        float v = e[d];
        ushort h = bf16_rne(v);
        eh[k * 64 + d] = h;
        el[k * 64 + d] = bf16_rne(v - bf16_f(h));
    }
    if (k == 0) { *cnt = 0u; out[QSIZE] = 0.f; out[QSIZE + 1] = 0.f; }
}

// ---- k1: MFMA 3-split approx dist + (m1,m2,i1) per row + certify-or-enqueue ----
// grid 512 x 256 (4 waves). Block owns 128 rows (one b, hw window of 128).
// Wave w owns 32 rows (2 tiles of 16). ct loop: 64 code-tiles of 16.
__launch_bounds__(256, 2)
__global__ void k1_mfma(const float* __restrict__ lat, const ushort* __restrict__ eh,
                        const ushort* __restrict__ el, const float* __restrict__ e2,
                        ushort* __restrict__ ind, unsigned* __restrict__ cnt,
                        ushort* __restrict__ list) {
    #pragma clang fp contract(off)
    __shared__ ushort xls[2][128][64];   // [split][row][d^((row&7)<<3)] bf16, 32 KB

    const int tid  = threadIdx.x;
    const int lane = tid & 63;
    const int w    = tid >> 6;
    const int lm   = lane & 15;          // MFMA col index (row-in-tile for A, code for B)
    const int lg   = lane >> 4;          // k-group
    const int br   = blockIdx.x;
    const int b    = br >> 3;
    const int hw0  = (br & 7) * 128;

    // ---- stage x -> LDS as bf16 hi/lo, [row][d] with XOR swizzle on d (16B units) ----
    {
        const float* latb = lat + (size_t)b * 65536 + hw0;
        #pragma unroll 4
        for (int i = 0; i < 32; ++i) {
            int idx = i * 256 + tid;     // 0..8191
            int d = idx >> 7, r = idx & 127;
            float v = latb[d * 1024 + r];
            ushort h = bf16_rne(v);
            ushort l2 = bf16_rne(v - bf16_f(h));
            int dsw = d ^ ((r & 7) << 3);
            xls[0][r][dsw] = h;
            xls[1][r][dsw] = l2;
        }
    }
    __syncthreads();

    // ---- A-fragments: 2 row-tiles x 2 k-halves x {hi,lo}; lane: m=lm, k=lg*8+kh*32+j ----
    short8 ah[2][2], al[2][2];
    #pragma unroll
    for (int rt = 0; rt < 2; ++rt) {
        int r = w * 32 + rt * 16 + lm;
        #pragma unroll
        for (int kh = 0; kh < 2; ++kh) {
            int d0 = (lg * 8 + kh * 32) ^ ((r & 7) << 3);
            ah[rt][kh] = *(const short8*)&xls[0][r][d0];
            al[rt][kh] = *(const short8*)&xls[1][r][d0];
        }
    }

    // ---- ct loop: 12 MFMAs per tile-pair, epilogue tracks (m1,m2,i1) per row ----
    const ushort* ehp = eh + lm * 64 + lg * 8;
    const ushort* elp = el + lm * 64 + lg * 8;
    float m1[2][4], m2[2][4];
    int   bi[2][4];
    #pragma unroll
    for (int rt = 0; rt < 2; ++rt)
        #pragma unroll
        for (int j = 0; j < 4; ++j) { m1[rt][j] = 3.4e38f; m2[rt][j] = 3.4e38f; bi[rt][j] = 0; }

    const f32x4 zero4 = {0.f, 0.f, 0.f, 0.f};
    short8 cbh0 = *(const short8*)(ehp);
    short8 cbh1 = *(const short8*)(ehp + 32);
    short8 cbl0 = *(const short8*)(elp);
    short8 cbl1 = *(const short8*)(elp + 32);
    float  ce2  = e2[lm];

    #pragma unroll 1
    for (int ct = 0; ct < 64; ++ct) {
        const int cto = (ct < 63 ? ct + 1 : 63) * 1024;     // prefetch (clamped)
        short8 nbh0 = *(const short8*)(ehp + cto);
        short8 nbh1 = *(const short8*)(ehp + cto + 32);
        short8 nbl0 = *(const short8*)(elp + cto);
        short8 nbl1 = *(const short8*)(elp + cto + 32);
        float  ne2  = e2[(ct < 63 ? ct + 1 : 63) * 16 + lm];

        f32x4 acc0, acc1;
        acc0 = __builtin_amdgcn_mfma_f32_16x16x32_bf16(ah[0][0], cbh0, zero4, 0, 0, 0);
        acc1 = __builtin_amdgcn_mfma_f32_16x16x32_bf16(ah[1][0], cbh0, zero4, 0, 0, 0);
        acc0 = __builtin_amdgcn_mfma_f32_16x16x32_bf16(ah[0][1], cbh1, acc0, 0, 0, 0);
        acc1 = __builtin_amdgcn_mfma_f32_16x16x32_bf16(ah[1][1], cbh1, acc1, 0, 0, 0);
        acc0 = __builtin_amdgcn_mfma_f32_16x16x32_bf16(ah[0][0], cbl0, acc0, 0, 0, 0);
        acc1 = __builtin_amdgcn_mfma_f32_16x16x32_bf16(ah[1][0], cbl0, acc1, 0, 0, 0);
        acc0 = __builtin_amdgcn_mfma_f32_16x16x32_bf16(ah[0][1], cbl1, acc0, 0, 0, 0);
        acc1 = __builtin_amdgcn_mfma_f32_16x16x32_bf16(ah[1][1], cbl1, acc1, 0, 0, 0);
        acc0 = __builtin_amdgcn_mfma_f32_16x16x32_bf16(al[0][0], cbh0, acc0, 0, 0, 0);
        acc1 = __builtin_amdgcn_mfma_f32_16x16x32_bf16(al[1][0], cbh0, acc1, 0, 0, 0);
        acc0 = __builtin_amdgcn_mfma_f32_16x16x32_bf16(al[0][1], cbh1, acc0, 0, 0, 0);
        acc1 = __builtin_amdgcn_mfma_f32_16x16x32_bf16(al[1][1], cbh1, acc1, 0, 0, 0);

        const int code = ct * 16 + lm;
        #pragma unroll
        for (int j = 0; j < 4; ++j) {
            {   // rt = 0
                float dv = __builtin_fmaf(-2.f, acc0[j], ce2);
                bool lt = dv < m1[0][j];
                m2[0][j] = lt ? m1[0][j] : fminf(m2[0][j], dv);
                bi[0][j] = lt ? code : bi[0][j];
                m1[0][j] = lt ? dv : m1[0][j];
            }
            {   // rt = 1
                float dv = __builtin_fmaf(-2.f, acc1[j], ce2);
                bool lt = dv < m1[1][j];
                m2[1][j] = lt ? m1[1][j] : fminf(m2[1][j], dv);
                bi[1][j] = lt ? code : bi[1][j];
                m1[1][j] = lt ? dv : m1[1][j];
            }
        }
        cbh0 = nbh0; cbh1 = nbh1; cbl0 = nbl0; cbl1 = nbl1; ce2 = ne2;
    }

    // ---- merge across the 16 lanes sharing each row; certify or enqueue ----
    #pragma unroll
    for (int rt = 0; rt < 2; ++rt) {
        #pragma unroll
        for (int j = 0; j < 4; ++j) {
            float M1 = m1[rt][j], M2 = m2[rt][j];
            int   I1 = bi[rt][j];
            #pragma unroll
            for (int m = 1; m <= 8; m <<= 1) {
                float om1 = __shfl_xor(M1, m, 64);
                float om2 = __shfl_xor(M2, m, 64);
                int   oi1 = __shfl_xor(I1, m, 64);
                bool take = (om1 < M1) || (om1 == M1 && oi1 < I1);
                float loser = take ? M1 : om1;
                M2 = fminf(fminf(M2, om2), loser);
                M1 = take ? om1 : M1;
                I1 = take ? oi1 : I1;
            }
            if (lm == 0) {
                int grow = br * 128 + w * 32 + rt * 16 + lg * 4 + j;
                if (M2 - M1 > THR) {
                    ind[grow] = (ushort)I1;
                } else {
                    unsigned p = atomicAdd(cnt, 1u);
                    list[p] = (ushort)grow;
                }
            }
        }
    }
}

// ---- k2: rescue — bit-exact f32-chain replica (round-2/8 proven numerics) on
//          flagged rows only. grid 64 x 512 (8 waves; wave scans 128 codes). ----
__launch_bounds__(512, 8)
__global__ void k2_rescue(const float* __restrict__ lat, const float* __restrict__ emb,
                          const float* __restrict__ e2, const unsigned* __restrict__ cnt,
                          const ushort* __restrict__ list, ushort* __restrict__ ind) {
    #pragma clang fp contract(off)
    __shared__ float2 xs2[32][64];
    __shared__ float  sm1[8][64];
    __shared__ int    sbi[8][64];
    __shared__ int    rl[64];

    const int tid  = threadIdx.x;
    const int lane = tid & 63;
    const int w    = tid >> 6;
    const unsigned n = *cnt;

    for (unsigned base = blockIdx.x * 64u; base < n; base += gridDim.x * 64u) {
        if (tid < 64) {
            unsigned idx = base + tid;
            rl[tid] = (int)list[idx < n ? idx : base];   // clamp duplicates (benign)
        }
        __syncthreads();

        const int rowL = rl[lane];
        const float* xg = lat + (size_t)(rowL >> 10) * 65536 + (rowL & 1023);
        #pragma unroll
        for (int i = 0; i < 8; ++i) {
            int d = i * 8 + w;                  // (i*512+tid)>>6
            ((float*)&xs2[d >> 1][lane])[d & 1] = xg[d * 1024];
        }
        __syncthreads();

        // x2 = numpy pairwise-8 replica
        float x2;
        {
            float r[8];
            #pragma unroll
            for (int j = 0; j < 8; ++j) {
                const float v = ((const float*)&xs2[j >> 1][lane])[j & 1];
                r[j] = v * v;
            }
            #pragma unroll
            for (int i = 8; i < 64; i += 8) {
                #pragma unroll
                for (int j = 0; j < 8; ++j) {
                    const float v = ((const float*)&xs2[(i + j) >> 1][lane])[(i + j) & 1];
                    r[j] = r[j] + v * v;
                }
            }
            x2 = ((r[0] + r[1]) + (r[2] + r[3])) + ((r[4] + r[5]) + (r[6] + r[7]));
        }

        const int kbase = __builtin_amdgcn_readfirstlane(w) << 7;
        float m1v = 3.4e38f;
        int   biv = kbase;
        #pragma unroll 1
        for (int kk = 0; kk < 128; kk += 4) {
            const float* ep = emb + (size_t)(kbase + kk) * 64;
            float c0 = 0.f, c1 = 0.f, c2 = 0.f, c3 = 0.f;
            #pragma unroll 2
            for (int dd = 0; dd < 32; ++dd) {
                const float2 xv = xs2[dd][lane];
                c0 = __builtin_fmaf(xv.x, ep[2*dd],       c0);
                c0 = __builtin_fmaf(xv.y, ep[2*dd + 1],   c0);
                c1 = __builtin_fmaf(xv.x, ep[64 + 2*dd],  c1);
                c1 = __builtin_fmaf(xv.y, ep[64 + 2*dd+1],c1);
                c2 = __builtin_fmaf(xv.x, ep[128 + 2*dd], c2);
                c2 = __builtin_fmaf(xv.y, ep[128+2*dd+1], c2);
                c3 = __builtin_fmaf(xv.x, ep[192 + 2*dd], c3);
                c3 = __builtin_fmaf(xv.y, ep[192+2*dd+1], c3);
            }
            const float e20 = e2[kbase + kk + 0];
            const float e21 = e2[kbase + kk + 1];
            const float e22 = e2[kbase + kk + 2];
            const float e23 = e2[kbase + kk + 3];
            const float t0 = x2 + e20; const float d0v = t0 - 2.0f * c0;
            const float t1 = x2 + e21; const float d1v = t1 - 2.0f * c1;
            const float t2 = x2 + e22; const float d2v = t2 - 2.0f * c2;
            const float t3 = x2 + e23; const float d3v = t3 - 2.0f * c3;
            if (d0v < m1v) { m1v = d0v; biv = kbase + kk + 0; }
            if (d1v < m1v) { m1v = d1v; biv = kbase + kk + 1; }
            if (d2v < m1v) { m1v = d2v; biv = kbase + kk + 2; }
            if (d3v < m1v) { m1v = d3v; biv = kbase + kk + 3; }
        }
        sm1[w][lane] = m1v;
        sbi[w][lane] = biv;
        __syncthreads();
        if (w == 0) {
            float M1 = sm1[0][lane];
            int   BI = sbi[0][lane];
            #pragma unroll
            for (int ww = 1; ww < 8; ++ww) {
                const float a = sm1[ww][lane];
                if (a < M1) { M1 = a; BI = sbi[ww][lane]; }
            }
            ind[rowL] = (ushort)BI;
        }
        __syncthreads();
    }
}

// ---- k3: q_out (straight-through replica) + losses + index-as-float ----
__launch_bounds__(256)
__global__ void k3_qout(const float* __restrict__ lat, const float* __restrict__ emb,
                        const ushort* __restrict__ ind, float* __restrict__ out) {
    #pragma clang fp contract(off)
    __shared__ float red[4];
    const int t = threadIdx.x;
    float sq = 0.f;
    #pragma unroll
    for (int i = 0; i < 8; ++i) {
        int g  = blockIdx.x * 2048 + i * 256 + t;
        int bb = g >> 16, d = (g >> 10) & 63, hw = g & 1023;
        int nidx = (bb << 10) + hw;
        int id = (int)ind[nidx];
        float q  = emb[id * 64 + d];
        float xv = lat[g];
        float qmx = q - xv;
        out[g] = xv + qmx;
        sq = __builtin_fmaf(qmx, qmx, sq);
        if (d == 0) out[QSIZE + 2 + nidx] = (float)id;
    }
    #pragma unroll
    for (int off = 32; off > 0; off >>= 1) sq += __shfl_down(sq, off, 64);
    if ((t & 63) == 0) red[t >> 6] = sq;
    __syncthreads();
    if (t == 0) {
        float p = ((red[0] + red[1]) + (red[2] + red[3])) * (1.0f / 4194304.0f);
        atomicAdd(&out[QSIZE],     p);
        atomicAdd(&out[QSIZE + 1], p);
    }
}

extern "C" void kernel_launch(void* const* d_in, const int* in_sizes, int n_in,
                              void* d_out, int out_size, void* d_ws, size_t ws_size,
                              hipStream_t stream) {
    const float* lat = (const float*)d_in[0];   // [64,64,32,32] f32
    const float* emb = (const float*)d_in[1];   // [1024,64] f32
    float* out = (float*)d_out;
    char*  ws  = (char*)d_ws;
    float*    e2   = (float*)(ws + WS_E2);
    ushort*   eh   = (ushort*)(ws + WS_EH);
    ushort*   el   = (ushort*)(ws + WS_EL);
    ushort*   ind  = (ushort*)(ws + WS_IND);
    unsigned* cnt  = (unsigned*)(ws + WS_CNT);
    ushort*   list = (ushort*)(ws + WS_LIST);

    hipLaunchKernelGGL(k0_prep,   dim3(4),    dim3(256), 0, stream, emb, e2, eh, el, cnt, out);
    hipLaunchKernelGGL(k1_mfma,   dim3(512),  dim3(256), 0, stream, lat, eh, el, e2, ind, cnt, list);
    hipLaunchKernelGGL(k2_rescue, dim3(64),   dim3(512), 0, stream, lat, emb, e2, cnt, list, ind);
    hipLaunchKernelGGL(k3_qout,   dim3(2048), dim3(256), 0, stream, lat, emb, ind, out);
}

// Round 10
// 310.869 us; speedup vs baseline: 1.0806x; 1.0806x over previous
//
#include <hip/hip_runtime.h>

#define QSIZE 4194304          // B*D*H*W
#define THR   1.5e-4f          // certification threshold (approx+ref-rounding bound x slack)

// ws layout (bytes)
#define WS_E2   0              // float[1024]
#define WS_EH   4096           // ushort[65536] bf16 hi of emb
#define WS_EL   135168         // ushort[65536] bf16 lo of emb
#define WS_IND  266240         // ushort[65536] argmin index per row
#define WS_CNT  397312         // uint rescue count
#define WS_LIST 397328         // ushort[65536] rescue row list

typedef __attribute__((ext_vector_type(8))) short short8;
typedef __attribute__((ext_vector_type(4))) float f32x4;

__device__ inline ushort bf16_rne(float v) {
    union { float f; unsigned u; } a; a.f = v;
    return (ushort)((a.u + 0x7FFFu + ((a.u >> 16) & 1u)) >> 16);
}
__device__ inline float bf16_f(ushort h) {
    union { unsigned u; float f; } a; a.u = ((unsigned)h) << 16;
    return a.f;
}

// ---- k0: coalesced via LDS bounce: e2 (numpy pairwise-8 replica) + bf16 split ----
// grid 16 x 256; block owns 64 codes.
__global__ void k0_prep(const float* __restrict__ emb, float* __restrict__ e2,
                        ushort* __restrict__ eh, ushort* __restrict__ el,
                        unsigned* __restrict__ cnt, float* __restrict__ out) {
    #pragma clang fp contract(off)
    __shared__ float ld[64][65];                 // +1 pad: conflict-free row reads
    const int tid = threadIdx.x;
    const int blk = blockIdx.x;
    #pragma unroll
    for (int i = 0; i < 16; ++i) {
        int idx = i * 256 + tid;                 // coalesced: emb[blk*4096 + idx]
        ld[idx >> 6][idx & 63] = emb[blk * 4096 + idx];
    }
    __syncthreads();
    if (tid < 64) {
        float rr[8];
        #pragma unroll
        for (int q = 0; q < 8; ++q) { float v = ld[tid][q]; rr[q] = v * v; }
        #pragma unroll
        for (int i = 8; i < 64; i += 8) {
            #pragma unroll
            for (int q = 0; q < 8; ++q) { float v = ld[tid][i + q]; rr[q] = rr[q] + v * v; }
        }
        e2[blk * 64 + tid] = ((rr[0] + rr[1]) + (rr[2] + rr[3])) + ((rr[4] + rr[5]) + (rr[6] + rr[7]));
    }
    #pragma unroll
    for (int i = 0; i < 16; ++i) {
        int idx = i * 256 + tid;
        float v = ld[idx >> 6][idx & 63];
        ushort h = bf16_rne(v);
        eh[blk * 4096 + idx] = h;
        el[blk * 4096 + idx] = bf16_rne(v - bf16_f(h));
    }
    if (blk == 0 && tid == 0) { *cnt = 0u; out[QSIZE] = 0.f; out[QSIZE + 1] = 0.f; }
}

// ---- k1: MFMA 3-split approx + (m1,m2,i1) + certify-or-enqueue ----
// grid 2048 x 256 (4 waves). Block owns 32 rows (one b). Wave w: codes [w*256,(w+1)*256).
__launch_bounds__(256, 4)
__global__ void k1_mfma(const float* __restrict__ lat, const ushort* __restrict__ eh,
                        const ushort* __restrict__ el, const float* __restrict__ e2,
                        ushort* __restrict__ ind, unsigned* __restrict__ cnt,
                        ushort* __restrict__ list) {
    __shared__ ushort xls[2][32][64];    // [split][row][d ^ ((row&7)<<3)] bf16, 8 KB
    __shared__ float  smm1[4][32], smm2[4][32];
    __shared__ ushort smbi[4][32];

    const int tid  = threadIdx.x;
    const int lane = tid & 63;
    const int w    = tid >> 6;
    const int lm   = lane & 15;          // A-row / B-col index
    const int lg   = lane >> 4;          // k-group
    const int br   = blockIdx.x;
    const int b    = br >> 5;
    const int hw0  = (br & 31) << 5;
    const int row0 = br << 5;

    // ---- stage x -> LDS bf16 hi/lo (coalesced 128B-chunk reads) ----
    {
        const float* latb = lat + (size_t)b * 65536 + hw0;
        #pragma unroll
        for (int i = 0; i < 8; ++i) {
            int idx = i * 256 + tid;     // 0..2047
            int d = idx >> 5, r = idx & 31;
            float v = latb[d * 1024 + r];
            ushort h = bf16_rne(v);
            ushort l = bf16_rne(v - bf16_f(h));
            int dsw = d ^ ((r & 7) << 3);
            xls[0][r][dsw] = h;
            xls[1][r][dsw] = l;
        }
    }
    __syncthreads();

    // ---- A-fragments as named regs: 2 row-tiles x 2 k-halves x {hi,lo} ----
    const int sw = (lm & 7) << 3;        // rows lm and 16+lm share (r&7)
    const int d0 = (lg * 8) ^ sw, d1 = (lg * 8 + 32) ^ sw;
    short8 ah00 = *(const short8*)&xls[0][lm][d0];
    short8 ah01 = *(const short8*)&xls[0][lm][d1];
    short8 ah10 = *(const short8*)&xls[0][16 + lm][d0];
    short8 ah11 = *(const short8*)&xls[0][16 + lm][d1];
    short8 al00 = *(const short8*)&xls[1][lm][d0];
    short8 al01 = *(const short8*)&xls[1][lm][d1];
    short8 al10 = *(const short8*)&xls[1][16 + lm][d0];
    short8 al11 = *(const short8*)&xls[1][16 + lm][d1];

    const ushort* ehp = eh + (((w << 8) + lm) << 6) + lg * 8;
    const ushort* elp = el + (((w << 8) + lm) << 6) + lg * 8;
    const float*  e2p = e2 + (w << 8) + lm;

    float m1a[4], m2a[4], m1b[4], m2b[4];
    int   bia[4], bib[4];
    #pragma unroll
    for (int j = 0; j < 4; ++j) {
        m1a[j] = 3.4e38f; m2a[j] = 3.4e38f; bia[j] = 0;
        m1b[j] = 3.4e38f; m2b[j] = 3.4e38f; bib[j] = 0;
    }

    const f32x4 zero4 = {0.f, 0.f, 0.f, 0.f};
    #pragma unroll 1
    for (int ct = 0; ct < 16; ++ct) {
        const int off = ct << 10;                 // 16 codes * 64 shorts
        short8 bh0 = *(const short8*)(ehp + off);
        short8 bh1 = *(const short8*)(ehp + off + 32);
        short8 bl0 = *(const short8*)(elp + off);
        short8 bl1 = *(const short8*)(elp + off + 32);
        const float ce2 = e2p[ct << 4];

        f32x4 acc0, acc1;
        acc0 = __builtin_amdgcn_mfma_f32_16x16x32_bf16(ah00, bh0, zero4, 0, 0, 0);
        acc1 = __builtin_amdgcn_mfma_f32_16x16x32_bf16(ah10, bh0, zero4, 0, 0, 0);
        acc0 = __builtin_amdgcn_mfma_f32_16x16x32_bf16(ah01, bh1, acc0, 0, 0, 0);
        acc1 = __builtin_amdgcn_mfma_f32_16x16x32_bf16(ah11, bh1, acc1, 0, 0, 0);
        acc0 = __builtin_amdgcn_mfma_f32_16x16x32_bf16(ah00, bl0, acc0, 0, 0, 0);
        acc1 = __builtin_amdgcn_mfma_f32_16x16x32_bf16(ah10, bl0, acc1, 0, 0, 0);
        acc0 = __builtin_amdgcn_mfma_f32_16x16x32_bf16(ah01, bl1, acc0, 0, 0, 0);
        acc1 = __builtin_amdgcn_mfma_f32_16x16x32_bf16(ah11, bl1, acc1, 0, 0, 0);
        acc0 = __builtin_amdgcn_mfma_f32_16x16x32_bf16(al00, bh0, acc0, 0, 0, 0);
        acc1 = __builtin_amdgcn_mfma_f32_16x16x32_bf16(al10, bh0, acc1, 0, 0, 0);
        acc0 = __builtin_amdgcn_mfma_f32_16x16x32_bf16(al01, bh1, acc0, 0, 0, 0);
        acc1 = __builtin_amdgcn_mfma_f32_16x16x32_bf16(al11, bh1, acc1, 0, 0, 0);

        const int code = (w << 8) + (ct << 4) + lm;
        #pragma unroll
        for (int j = 0; j < 4; ++j) {
            {   // row tile 0 (rows lm ... via C-layout row = lg*4+j)
                float dv = __builtin_fmaf(-2.f, acc0[j], ce2);
                bool lt = dv < m1a[j];
                m2a[j] = lt ? m1a[j] : fminf(m2a[j], dv);
                bia[j] = lt ? code : bia[j];
                m1a[j] = lt ? dv : m1a[j];
            }
            {   // row tile 1
                float dv = __builtin_fmaf(-2.f, acc1[j], ce2);
                bool lt = dv < m1b[j];
                m2b[j] = lt ? m1b[j] : fminf(m2b[j], dv);
                bib[j] = lt ? code : bib[j];
                m1b[j] = lt ? dv : m1b[j];
            }
        }
    }

    // ---- merge across the 16 lanes sharing each row, store per-wave result ----
    #pragma unroll
    for (int rt = 0; rt < 2; ++rt) {
        #pragma unroll
        for (int j = 0; j < 4; ++j) {
            float M1 = rt ? m1b[j] : m1a[j];
            float M2 = rt ? m2b[j] : m2a[j];
            int   I1 = rt ? bib[j] : bia[j];
            #pragma unroll
            for (int m = 1; m <= 8; m <<= 1) {
                float o1 = __shfl_xor(M1, m, 64);
                float o2 = __shfl_xor(M2, m, 64);
                int   oi = __shfl_xor(I1, m, 64);
                bool take = (o1 < M1) || (o1 == M1 && oi < I1);
                float loser = take ? M1 : o1;
                M2 = fminf(fminf(M2, o2), loser);
                M1 = take ? o1 : M1;
                I1 = take ? oi : I1;
            }
            if (lm == 0) {
                int rr = rt * 16 + lg * 4 + j;
                smm1[w][rr] = M1; smm2[w][rr] = M2; smbi[w][rr] = (ushort)I1;
            }
        }
    }
    __syncthreads();

    // ---- cross-wave merge (ascending code quarters), certify or enqueue ----
    if (tid < 32) {
        float M1 = smm1[0][tid], M2 = smm2[0][tid];
        int   I1 = smbi[0][tid];
        #pragma unroll
        for (int ww = 1; ww < 4; ++ww) {
            float a1 = smm1[ww][tid], a2 = smm2[ww][tid];
            int   ai = smbi[ww][tid];
            if (a1 < M1) { M2 = fminf(M1, a2); M1 = a1; I1 = ai; }
            else         { M2 = fminf(M2, a1); }
        }
        ind[row0 + tid] = (ushort)I1;
        if (!(M2 - M1 > THR)) {
            unsigned p = atomicAdd(cnt, 1u);
            list[p] = (ushort)(row0 + tid);
        }
    }
}

// ---- k2: rescue — bit-exact f32-chain replica on flagged rows (grid 256 now) ----
__launch_bounds__(512, 8)
__global__ void k2_rescue(const float* __restrict__ lat, const float* __restrict__ emb,
                          const float* __restrict__ e2, const unsigned* __restrict__ cnt,
                          const ushort* __restrict__ list, ushort* __restrict__ ind) {
    #pragma clang fp contract(off)
    __shared__ float2 xs2[32][64];
    __shared__ float  sm1[8][64];
    __shared__ int    sbi[8][64];
    __shared__ int    rl[64];

    const int tid  = threadIdx.x;
    const int lane = tid & 63;
    const int w    = tid >> 6;
    const unsigned n = *cnt;

    for (unsigned base = blockIdx.x * 64u; base < n; base += gridDim.x * 64u) {
        if (tid < 64) {
            unsigned idx = base + tid;
            rl[tid] = (int)list[idx < n ? idx : base];   // clamp duplicates (benign)
        }
        __syncthreads();

        const int rowL = rl[lane];
        const float* xg = lat + (size_t)(rowL >> 10) * 65536 + (rowL & 1023);
        #pragma unroll
        for (int i = 0; i < 8; ++i) {
            int d = i * 8 + w;
            ((float*)&xs2[d >> 1][lane])[d & 1] = xg[d * 1024];
        }
        __syncthreads();

        // x2 = numpy pairwise-8 replica
        float x2;
        {
            float r[8];
            #pragma unroll
            for (int j = 0; j < 8; ++j) {
                const float v = ((const float*)&xs2[j >> 1][lane])[j & 1];
                r[j] = v * v;
            }
            #pragma unroll
            for (int i = 8; i < 64; i += 8) {
                #pragma unroll
                for (int j = 0; j < 8; ++j) {
                    const float v = ((const float*)&xs2[(i + j) >> 1][lane])[(i + j) & 1];
                    r[j] = r[j] + v * v;
                }
            }
            x2 = ((r[0] + r[1]) + (r[2] + r[3])) + ((r[4] + r[5]) + (r[6] + r[7]));
        }

        const int kbase = __builtin_amdgcn_readfirstlane(w) << 7;
        float m1v = 3.4e38f;
        int   biv = kbase;
        #pragma unroll 1
        for (int kk = 0; kk < 128; kk += 4) {
            const float* ep = emb + (size_t)(kbase + kk) * 64;
            float c0 = 0.f, c1 = 0.f, c2 = 0.f, c3 = 0.f;
            #pragma unroll 2
            for (int dd = 0; dd < 32; ++dd) {
                const float2 xv = xs2[dd][lane];
                c0 = __builtin_fmaf(xv.x, ep[2*dd],        c0);
                c0 = __builtin_fmaf(xv.y, ep[2*dd + 1],    c0);
                c1 = __builtin_fmaf(xv.x, ep[64 + 2*dd],   c1);
                c1 = __builtin_fmaf(xv.y, ep[64 + 2*dd+1], c1);
                c2 = __builtin_fmaf(xv.x, ep[128 + 2*dd],  c2);
                c2 = __builtin_fmaf(xv.y, ep[128+2*dd+1],  c2);
                c3 = __builtin_fmaf(xv.x, ep[192 + 2*dd],  c3);
                c3 = __builtin_fmaf(xv.y, ep[192+2*dd+1],  c3);
            }
            const float e20 = e2[kbase + kk + 0];
            const float e21 = e2[kbase + kk + 1];
            const float e22 = e2[kbase + kk + 2];
            const float e23 = e2[kbase + kk + 3];
            const float t0 = x2 + e20; const float d0v = t0 - 2.0f * c0;
            const float t1 = x2 + e21; const float d1v = t1 - 2.0f * c1;
            const float t2 = x2 + e22; const float d2v = t2 - 2.0f * c2;
            const float t3 = x2 + e23; const float d3v = t3 - 2.0f * c3;
            if (d0v < m1v) { m1v = d0v; biv = kbase + kk + 0; }
            if (d1v < m1v) { m1v = d1v; biv = kbase + kk + 1; }
            if (d2v < m1v) { m1v = d2v; biv = kbase + kk + 2; }
            if (d3v < m1v) { m1v = d3v; biv = kbase + kk + 3; }
        }
        sm1[w][lane] = m1v;
        sbi[w][lane] = biv;
        __syncthreads();
        if (w == 0) {
            float M1 = sm1[0][lane];
            int   BI = sbi[0][lane];
            #pragma unroll
            for (int ww = 1; ww < 8; ++ww) {
                const float a = sm1[ww][lane];
                if (a < M1) { M1 = a; BI = sbi[ww][lane]; }
            }
            ind[rowL] = (ushort)BI;
        }
        __syncthreads();
    }
}

// ---- k3: q_out (straight-through replica) + losses + index-as-float ----
__launch_bounds__(256)
__global__ void k3_qout(const float* __restrict__ lat, const float* __restrict__ emb,
                        const ushort* __restrict__ ind, float* __restrict__ out) {
    #pragma clang fp contract(off)
    __shared__ float red[4];
    const int t = threadIdx.x;
    float sq = 0.f;
    #pragma unroll
    for (int i = 0; i < 8; ++i) {
        int g  = blockIdx.x * 2048 + i * 256 + t;
        int bb = g >> 16, d = (g >> 10) & 63, hw = g & 1023;
        int nidx = (bb << 10) + hw;
        int id = (int)ind[nidx];
        float q  = emb[id * 64 + d];
        float xv = lat[g];
        float qmx = q - xv;
        out[g] = xv + qmx;
        sq = __builtin_fmaf(qmx, qmx, sq);
        if (d == 0) out[QSIZE + 2 + nidx] = (float)id;
    }
    #pragma unroll
    for (int off = 32; off > 0; off >>= 1) sq += __shfl_down(sq, off, 64);
    if ((t & 63) == 0) red[t >> 6] = sq;
    __syncthreads();
    if (t == 0) {
        float p = ((red[0] + red[1]) + (red[2] + red[3])) * (1.0f / 4194304.0f);
        atomicAdd(&out[QSIZE],     p);
        atomicAdd(&out[QSIZE + 1], p);
    }
}

extern "C" void kernel_launch(void* const* d_in, const int* in_sizes, int n_in,
                              void* d_out, int out_size, void* d_ws, size_t ws_size,
                              hipStream_t stream) {
    const float* lat = (const float*)d_in[0];   // [64,64,32,32] f32
    const float* emb = (const float*)d_in[1];   // [1024,64] f32
    float* out = (float*)d_out;
    char*  ws  = (char*)d_ws;
    float*    e2   = (float*)(ws + WS_E2);
    ushort*   eh   = (ushort*)(ws + WS_EH);
    ushort*   el   = (ushort*)(ws + WS_EL);
    ushort*   ind  = (ushort*)(ws + WS_IND);
    unsigned* cnt  = (unsigned*)(ws + WS_CNT);
    ushort*   list = (ushort*)(ws + WS_LIST);

    hipLaunchKernelGGL(k0_prep,   dim3(16),   dim3(256), 0, stream, emb, e2, eh, el, cnt, out);
    hipLaunchKernelGGL(k1_mfma,   dim3(2048), dim3(256), 0, stream, lat, eh, el, e2, ind, cnt, list);
    hipLaunchKernelGGL(k2_rescue, dim3(256),  dim3(512), 0, stream, lat, emb, e2, cnt, list, ind);
    hipLaunchKernelGGL(k3_qout,   dim3(2048), dim3(256), 0, stream, lat, emb, ind, out);
}

// Round 11
// 229.623 us; speedup vs baseline: 1.4629x; 1.3538x over previous
//
#include <hip/hip_runtime.h>

#define QSIZE 4194304          // B*D*H*W
#define THR   1.5e-4f          // certification threshold (approx+ref-rounding bound x slack)

// ws layout (bytes)
#define WS_E2   0              // float[1024]
#define WS_EH   4096           // ushort[65536] bf16 hi of emb
#define WS_EL   135168         // ushort[65536] bf16 lo of emb
#define WS_IND  266240         // ushort[65536] approx argmin per row (k1)
#define WS_CNT  397312         // uint rescue count
#define WS_LIST 397328         // ushort[65536] rescue row list
#define WS_NEW  528400         // ushort[65536] exact argmin per list position (k2)

typedef __attribute__((ext_vector_type(8))) short short8;
typedef __attribute__((ext_vector_type(4))) float f32x4;

__device__ inline ushort bf16_rne(float v) {
    union { float f; unsigned u; } a; a.f = v;
    return (ushort)((a.u + 0x7FFFu + ((a.u >> 16) & 1u)) >> 16);
}
__device__ inline float bf16_f(ushort h) {
    union { unsigned u; float f; } a; a.u = ((unsigned)h) << 16;
    return a.f;
}

// ---- k0: coalesced via LDS bounce: e2 (numpy pairwise-8 replica) + bf16 split ----
__global__ void k0_prep(const float* __restrict__ emb, float* __restrict__ e2,
                        ushort* __restrict__ eh, ushort* __restrict__ el,
                        unsigned* __restrict__ cnt, float* __restrict__ out) {
    #pragma clang fp contract(off)
    __shared__ float ld[64][65];
    const int tid = threadIdx.x;
    const int blk = blockIdx.x;
    #pragma unroll
    for (int i = 0; i < 16; ++i) {
        int idx = i * 256 + tid;
        ld[idx >> 6][idx & 63] = emb[blk * 4096 + idx];
    }
    __syncthreads();
    if (tid < 64) {
        float rr[8];
        #pragma unroll
        for (int q = 0; q < 8; ++q) { float v = ld[tid][q]; rr[q] = v * v; }
        #pragma unroll
        for (int i = 8; i < 64; i += 8) {
            #pragma unroll
            for (int q = 0; q < 8; ++q) { float v = ld[tid][i + q]; rr[q] = rr[q] + v * v; }
        }
        e2[blk * 64 + tid] = ((rr[0] + rr[1]) + (rr[2] + rr[3])) + ((rr[4] + rr[5]) + (rr[6] + rr[7]));
    }
    #pragma unroll
    for (int i = 0; i < 16; ++i) {
        int idx = i * 256 + tid;
        float v = ld[idx >> 6][idx & 63];
        ushort h = bf16_rne(v);
        eh[blk * 4096 + idx] = h;
        el[blk * 4096 + idx] = bf16_rne(v - bf16_f(h));
    }
    if (blk == 0 && tid == 0) { *cnt = 0u; out[QSIZE] = 0.f; out[QSIZE + 1] = 0.f; }
}

// ---- k1: MFMA 3-split approx + certify-or-enqueue + FUSED q_out/loss/index epilogue ----
// grid 2048 x 256 (4 waves). Block owns 32 rows (one b). Wave w: codes [w*256,(w+1)*256).
__launch_bounds__(256, 4)
__global__ void k1_mfma(const float* __restrict__ lat, const ushort* __restrict__ eh,
                        const ushort* __restrict__ el, const float* __restrict__ e2,
                        const float* __restrict__ emb, float* __restrict__ out,
                        ushort* __restrict__ ind, unsigned* __restrict__ cnt,
                        ushort* __restrict__ list) {
    #pragma clang fp contract(off)
    __shared__ ushort xls[2][32][64];    // [split][row][d ^ ((row&7)<<3)] bf16, 8 KB
    __shared__ float  smm1[4][32], smm2[4][32];
    __shared__ ushort smbi[4][32];
    __shared__ int    smIdx[32];
    __shared__ float  red[4];

    const int tid  = threadIdx.x;
    const int lane = tid & 63;
    const int w    = tid >> 6;
    const int lm   = lane & 15;
    const int lg   = lane >> 4;
    const int br   = blockIdx.x;
    const int b    = br >> 5;
    const int hw0  = (br & 31) << 5;
    const int row0 = br << 5;

    // ---- stage x -> LDS bf16 hi/lo ----
    const float* latb = lat + (size_t)b * 65536 + hw0;
    {
        #pragma unroll
        for (int i = 0; i < 8; ++i) {
            int idx = i * 256 + tid;     // 0..2047
            int d = idx >> 5, r = idx & 31;
            float v = latb[d * 1024 + r];
            ushort h = bf16_rne(v);
            ushort l = bf16_rne(v - bf16_f(h));
            int dsw = d ^ ((r & 7) << 3);
            xls[0][r][dsw] = h;
            xls[1][r][dsw] = l;
        }
    }
    __syncthreads();

    // ---- A-fragments as named regs: 2 row-tiles x 2 k-halves x {hi,lo} ----
    const int sw = (lm & 7) << 3;
    const int d0 = (lg * 8) ^ sw, d1 = (lg * 8 + 32) ^ sw;
    short8 ah00 = *(const short8*)&xls[0][lm][d0];
    short8 ah01 = *(const short8*)&xls[0][lm][d1];
    short8 ah10 = *(const short8*)&xls[0][16 + lm][d0];
    short8 ah11 = *(const short8*)&xls[0][16 + lm][d1];
    short8 al00 = *(const short8*)&xls[1][lm][d0];
    short8 al01 = *(const short8*)&xls[1][lm][d1];
    short8 al10 = *(const short8*)&xls[1][16 + lm][d0];
    short8 al11 = *(const short8*)&xls[1][16 + lm][d1];

    const ushort* ehp = eh + (((w << 8) + lm) << 6) + lg * 8;
    const ushort* elp = el + (((w << 8) + lm) << 6) + lg * 8;
    const float*  e2p = e2 + (w << 8) + lm;

    float m1a[4], m2a[4], m1b[4], m2b[4];
    int   bia[4], bib[4];
    #pragma unroll
    for (int j = 0; j < 4; ++j) {
        m1a[j] = 3.4e38f; m2a[j] = 3.4e38f; bia[j] = 0;
        m1b[j] = 3.4e38f; m2b[j] = 3.4e38f; bib[j] = 0;
    }

    const f32x4 zero4 = {0.f, 0.f, 0.f, 0.f};
    #pragma unroll 1
    for (int ct = 0; ct < 16; ++ct) {
        const int off = ct << 10;
        short8 bh0 = *(const short8*)(ehp + off);
        short8 bh1 = *(const short8*)(ehp + off + 32);
        short8 bl0 = *(const short8*)(elp + off);
        short8 bl1 = *(const short8*)(elp + off + 32);
        const float ce2 = e2p[ct << 4];

        f32x4 acc0, acc1;
        acc0 = __builtin_amdgcn_mfma_f32_16x16x32_bf16(ah00, bh0, zero4, 0, 0, 0);
        acc1 = __builtin_amdgcn_mfma_f32_16x16x32_bf16(ah10, bh0, zero4, 0, 0, 0);
        acc0 = __builtin_amdgcn_mfma_f32_16x16x32_bf16(ah01, bh1, acc0, 0, 0, 0);
        acc1 = __builtin_amdgcn_mfma_f32_16x16x32_bf16(ah11, bh1, acc1, 0, 0, 0);
        acc0 = __builtin_amdgcn_mfma_f32_16x16x32_bf16(ah00, bl0, acc0, 0, 0, 0);
        acc1 = __builtin_amdgcn_mfma_f32_16x16x32_bf16(ah10, bl0, acc1, 0, 0, 0);
        acc0 = __builtin_amdgcn_mfma_f32_16x16x32_bf16(ah01, bl1, acc0, 0, 0, 0);
        acc1 = __builtin_amdgcn_mfma_f32_16x16x32_bf16(ah11, bl1, acc1, 0, 0, 0);
        acc0 = __builtin_amdgcn_mfma_f32_16x16x32_bf16(al00, bh0, acc0, 0, 0, 0);
        acc1 = __builtin_amdgcn_mfma_f32_16x16x32_bf16(al10, bh0, acc1, 0, 0, 0);
        acc0 = __builtin_amdgcn_mfma_f32_16x16x32_bf16(al01, bh1, acc0, 0, 0, 0);
        acc1 = __builtin_amdgcn_mfma_f32_16x16x32_bf16(al11, bh1, acc1, 0, 0, 0);

        const int code = (w << 8) + (ct << 4) + lm;
        #pragma unroll
        for (int j = 0; j < 4; ++j) {
            {
                float dv = __builtin_fmaf(-2.f, acc0[j], ce2);
                bool lt = dv < m1a[j];
                m2a[j] = lt ? m1a[j] : fminf(m2a[j], dv);
                bia[j] = lt ? code : bia[j];
                m1a[j] = lt ? dv : m1a[j];
            }
            {
                float dv = __builtin_fmaf(-2.f, acc1[j], ce2);
                bool lt = dv < m1b[j];
                m2b[j] = lt ? m1b[j] : fminf(m2b[j], dv);
                bib[j] = lt ? code : bib[j];
                m1b[j] = lt ? dv : m1b[j];
            }
        }
    }

    // ---- merge across 16 lanes sharing each row ----
    #pragma unroll
    for (int rt = 0; rt < 2; ++rt) {
        #pragma unroll
        for (int j = 0; j < 4; ++j) {
            float M1 = rt ? m1b[j] : m1a[j];
            float M2 = rt ? m2b[j] : m2a[j];
            int   I1 = rt ? bib[j] : bia[j];
            #pragma unroll
            for (int m = 1; m <= 8; m <<= 1) {
                float o1 = __shfl_xor(M1, m, 64);
                float o2 = __shfl_xor(M2, m, 64);
                int   oi = __shfl_xor(I1, m, 64);
                bool take = (o1 < M1) || (o1 == M1 && oi < I1);
                float loser = take ? M1 : o1;
                M2 = fminf(fminf(M2, o2), loser);
                M1 = take ? o1 : M1;
                I1 = take ? oi : I1;
            }
            if (lm == 0) {
                int rr = rt * 16 + lg * 4 + j;
                smm1[w][rr] = M1; smm2[w][rr] = M2; smbi[w][rr] = (ushort)I1;
            }
        }
    }
    __syncthreads();

    // ---- cross-wave merge, certify or enqueue, record final approx index ----
    if (tid < 32) {
        float M1 = smm1[0][tid], M2 = smm2[0][tid];
        int   I1 = smbi[0][tid];
        #pragma unroll
        for (int ww = 1; ww < 4; ++ww) {
            float a1 = smm1[ww][tid], a2 = smm2[ww][tid];
            int   ai = smbi[ww][tid];
            if (a1 < M1) { M2 = fminf(M1, a2); M1 = a1; I1 = ai; }
            else         { M2 = fminf(M2, a1); }
        }
        ind[row0 + tid] = (ushort)I1;
        smIdx[tid] = I1;
        out[QSIZE + 2 + row0 + tid] = (float)I1;
        if (!(M2 - M1 > THR)) {
            unsigned p = atomicAdd(cnt, 1u);
            list[p] = (ushort)(row0 + tid);
        }
    }
    __syncthreads();

    // ---- fused epilogue: q_out (straight-through) + loss partial ----
    {
        const int r = tid & 31;
        const int id = smIdx[r];
        float sq = 0.f;
        #pragma unroll
        for (int i = 0; i < 8; ++i) {
            const int d = i * 8 + (tid >> 5);
            const float xv = latb[d * 1024 + r];
            const float qv = emb[id * 64 + d];
            const float qmx = qv - xv;
            out[(size_t)b * 65536 + d * 1024 + hw0 + r] = xv + qmx;
            sq = __builtin_fmaf(qmx, qmx, sq);
        }
        #pragma unroll
        for (int off = 32; off > 0; off >>= 1) sq += __shfl_down(sq, off, 64);
        if (lane == 0) red[w] = sq;
    }
    __syncthreads();
    if (tid == 0) {
        const float p = ((red[0] + red[1]) + (red[2] + red[3])) * (1.0f / 4194304.0f);
        atomicAdd(&out[QSIZE],     p);
        atomicAdd(&out[QSIZE + 1], p);
    }
}

// ---- k2: exact f32-chain argmin on flagged rows; 16-row groups, 8 waves ----
// Wave w: codes [w*128,(w+1)*128); lane = cg*16 + r; cg covers 32 codes (8 quads).
__launch_bounds__(512, 8)
__global__ void k2_exact(const float* __restrict__ lat, const float* __restrict__ emb,
                         const float* __restrict__ e2, const unsigned* __restrict__ cnt,
                         const ushort* __restrict__ list, ushort* __restrict__ newind) {
    #pragma clang fp contract(off)
    __shared__ float xs[16][66];
    __shared__ float sx2[16];
    __shared__ unsigned long long sm[8][16];
    __shared__ int rl[16];

    const int tid  = threadIdx.x;
    const int lane = tid & 63;
    const int w    = tid >> 6;
    const unsigned n = *cnt;
    const unsigned ngroups = (n + 15u) >> 4;

    for (unsigned g = blockIdx.x; g < ngroups; g += gridDim.x) {
        if (tid < 16) {
            unsigned p = g * 16u + (unsigned)tid;
            rl[tid] = (int)list[p < n ? p : (n - 1u)];
        }
        __syncthreads();
        {   // stage exact f32 x rows (2 elems/thread)
            int r = tid & 15, dbase = tid >> 4;          // dbase 0..31
            int rowL = rl[r];
            const float* xg = lat + (size_t)(rowL >> 10) * 65536 + (rowL & 1023);
            xs[r][dbase]      = xg[dbase * 1024];
            xs[r][dbase + 32] = xg[(dbase + 32) * 1024];
        }
        __syncthreads();
        if (tid < 16) {   // x2 = numpy pairwise-8 replica
            float rr[8];
            #pragma unroll
            for (int q = 0; q < 8; ++q) { float v = xs[tid][q]; rr[q] = v * v; }
            #pragma unroll
            for (int i = 8; i < 64; i += 8) {
                #pragma unroll
                for (int q = 0; q < 8; ++q) { float v = xs[tid][i + q]; rr[q] = rr[q] + v * v; }
            }
            sx2[tid] = ((rr[0] + rr[1]) + (rr[2] + rr[3])) + ((rr[4] + rr[5]) + (rr[6] + rr[7]));
        }
        __syncthreads();

        const int r = lane & 15, cg = lane >> 4;
        const float x2v = sx2[r];
        unsigned long long best = ~0ULL;
        #pragma unroll 1
        for (int q4 = 0; q4 < 8; ++q4) {
            const int k0 = (w << 7) + (cg << 5) + (q4 << 2);
            const float* ep = emb + (size_t)k0 * 64;
            float c0 = 0.f, c1 = 0.f, c2 = 0.f, c3 = 0.f;
            #pragma unroll 2
            for (int dd = 0; dd < 32; ++dd) {
                const float2 xv = *(const float2*)&xs[r][2 * dd];
                c0 = __builtin_fmaf(xv.x, ep[2*dd],        c0);
                c0 = __builtin_fmaf(xv.y, ep[2*dd + 1],    c0);
                c1 = __builtin_fmaf(xv.x, ep[64 + 2*dd],   c1);
                c1 = __builtin_fmaf(xv.y, ep[64 + 2*dd+1], c1);
                c2 = __builtin_fmaf(xv.x, ep[128 + 2*dd],  c2);
                c2 = __builtin_fmaf(xv.y, ep[128+2*dd+1],  c2);
                c3 = __builtin_fmaf(xv.x, ep[192 + 2*dd],  c3);
                c3 = __builtin_fmaf(xv.y, ep[192+2*dd+1],  c3);
            }
            // dist = fl(fl(x2+e2) - 2c); positive -> f32 bits are order-monotone
            #pragma unroll
            for (int j = 0; j < 4; ++j) {
                float cj = j == 0 ? c0 : (j == 1 ? c1 : (j == 2 ? c2 : c3));
                float t  = x2v + e2[k0 + j];
                float dv = t - 2.0f * cj;
                union { float f; unsigned u; } cv; cv.f = dv;
                unsigned long long pk = ((unsigned long long)cv.u << 16) | (unsigned)(k0 + j);
                best = pk < best ? pk : best;
            }
        }
        // merge the 4 code-groups sharing each row (xor 16, 32 keeps r fixed)
        {
            unsigned long long o = __shfl_xor(best, 16, 64); best = o < best ? o : best;
            o = __shfl_xor(best, 32, 64);                    best = o < best ? o : best;
        }
        if (lane < 16) sm[w][lane] = best;
        __syncthreads();
        if (w == 0 && lane < 16) {
            unsigned long long m = sm[0][lane];
            #pragma unroll
            for (int ww = 1; ww < 8; ++ww) { unsigned long long o = sm[ww][lane]; m = o < m ? o : m; }
            unsigned p = g * 16u + (unsigned)lane;
            if (p < n) newind[p] = (ushort)(m & 0xFFFFu);
        }
        __syncthreads();
    }
}

// ---- k3_fix: rewrite rows where exact argmin differs from approx ----
__launch_bounds__(256)
__global__ void k3_fix(const float* __restrict__ lat, const float* __restrict__ emb,
                       const unsigned* __restrict__ cnt, const ushort* __restrict__ list,
                       const ushort* __restrict__ newind, const ushort* __restrict__ ind,
                       float* __restrict__ out) {
    #pragma clang fp contract(off)
    const unsigned n = *cnt;
    for (unsigned p = blockIdx.x * 256u + threadIdx.x; p < n; p += gridDim.x * 256u) {
        const int In = (int)newind[p];
        const int row = (int)list[p];
        const int Io = (int)ind[row];
        if (In == Io) continue;
        const int bb = row >> 10, hw = row & 1023;
        const float* xg = lat + (size_t)bb * 65536 + hw;
        const float* qo = emb + Io * 64;
        const float* qn = emb + In * 64;
        float dn = 0.f, do_ = 0.f;
        #pragma unroll 4
        for (int d = 0; d < 64; ++d) {
            const float xv = xg[d * 1024];
            const float a = qn[d] - xv;
            const float bvv = qo[d] - xv;
            out[(size_t)bb * 65536 + d * 1024 + hw] = xv + a;
            dn = __builtin_fmaf(a, a, dn);
            do_ = __builtin_fmaf(bvv, bvv, do_);
        }
        out[QSIZE + 2 + row] = (float)In;
        const float delta = (dn - do_) * (1.0f / 4194304.0f);
        atomicAdd(&out[QSIZE],     delta);
        atomicAdd(&out[QSIZE + 1], delta);
    }
}

extern "C" void kernel_launch(void* const* d_in, const int* in_sizes, int n_in,
                              void* d_out, int out_size, void* d_ws, size_t ws_size,
                              hipStream_t stream) {
    const float* lat = (const float*)d_in[0];   // [64,64,32,32] f32
    const float* emb = (const float*)d_in[1];   // [1024,64] f32
    float* out = (float*)d_out;
    char*  ws  = (char*)d_ws;
    float*    e2   = (float*)(ws + WS_E2);
    ushort*   eh   = (ushort*)(ws + WS_EH);
    ushort*   el   = (ushort*)(ws + WS_EL);
    ushort*   ind  = (ushort*)(ws + WS_IND);
    unsigned* cnt  = (unsigned*)(ws + WS_CNT);
    ushort*   list = (ushort*)(ws + WS_LIST);
    ushort*   newi = (ushort*)(ws + WS_NEW);

    hipLaunchKernelGGL(k0_prep,  dim3(16),   dim3(256), 0, stream, emb, e2, eh, el, cnt, out);
    hipLaunchKernelGGL(k1_mfma,  dim3(2048), dim3(256), 0, stream, lat, eh, el, e2, emb, out, ind, cnt, list);
    hipLaunchKernelGGL(k2_exact, dim3(512),  dim3(512), 0, stream, lat, emb, e2, cnt, list, newi);
    hipLaunchKernelGGL(k3_fix,   dim3(64),   dim3(256), 0, stream, lat, emb, cnt, list, newi, ind, out);
}